// Round 13
// baseline (160.945 us; speedup 1.0000x reference)
//
#include <hip/hip_runtime.h>
#include <math.h>

using f32x4   = __attribute__((ext_vector_type(4))) float;
using bf16x8  = __attribute__((ext_vector_type(8))) short;

constexpr int Bb = 2;
constexpr int T  = 2048;
constexpr int D  = 768;
constexpr int H  = 12;
constexpr int Dh = 64;
constexpr int M  = Bb * T;        // 4096
constexpr int NQKV = 3 * D;       // 2304
constexpr int NBH = Bb * H;       // 24
// fold 1/sqrt(Dh) * log2(e) into Q so attention uses exp2 directly
#define SCALE_Q 0.18033688011112042f

// ---------------------------------------------------------------------------
// helpers
// ---------------------------------------------------------------------------
__device__ __forceinline__ unsigned short f2bf(float f) {
    unsigned u = __float_as_uint(f);
    u += 0x7fffu + ((u >> 16) & 1u);      // RNE
    return (unsigned short)(u >> 16);
}

__device__ __forceinline__ ushort4 f2bf4(float4 f) {
    return make_ushort4(f2bf(f.x), f2bf(f.y), f2bf(f.z), f2bf(f.w));
}

// truncate-pack two fp32 -> packed bf16x2 in ONE v_perm_b32:
// result = { hi16(hi_f), hi16(lo_f) }
__device__ __forceinline__ unsigned permpk(float hi_f, float lo_f) {
    return __builtin_amdgcn_perm(__float_as_uint(hi_f), __float_as_uint(lo_f),
                                 0x07060302u);
}

// async global->LDS, 16B per lane; lds base must be wave-uniform (HW scatters
// lane l's data to base + l*16)
__device__ __forceinline__ void async_copy16(const void* g, void* lds_base) {
    __builtin_amdgcn_global_load_lds(
        (const __attribute__((address_space(1))) unsigned int*)g,
        (__attribute__((address_space(3))) unsigned int*)lds_base, 16, 0, 0);
}

// ---------------------------------------------------------------------------
// Prep: fp32 -> bf16 for X, stacked Wqkv, Wo; stack biases (fp32)
// ---------------------------------------------------------------------------
__global__ __launch_bounds__(256) void prep_kernel(
    const float4* __restrict__ x,
    const float4* __restrict__ Wq, const float4* __restrict__ Wk,
    const float4* __restrict__ Wv, const float4* __restrict__ Wo,
    const float* __restrict__ bq, const float* __restrict__ bk, const float* __restrict__ bv,
    ushort4* __restrict__ Xb, ushort4* __restrict__ Wqkvb, ushort4* __restrict__ Wob,
    float* __restrict__ biasS)
{
    const int stride = gridDim.x * 256;
    const int i0 = blockIdx.x * 256 + threadIdx.x;
    const int NX = M * D / 4;       // 786432
    const int NW = D * D / 4;       // 147456
    for (int i = i0; i < NX; i += stride) Xb[i] = f2bf4(x[i]);
    for (int i = i0; i < NW; i += stride) {
        Wqkvb[i]          = f2bf4(Wq[i]);
        Wqkvb[NW + i]     = f2bf4(Wk[i]);
        Wqkvb[2 * NW + i] = f2bf4(Wv[i]);
        Wob[i]            = f2bf4(Wo[i]);
    }
    for (int i = i0; i < D; i += stride) {
        biasS[i]         = bq[i];
        biasS[D + i]     = bk[i];
        biasS[2 * D + i] = bv[i];
    }
}

// ---------------------------------------------------------------------------
// bf16 GEMM (B^T layout): C[m,n] = sum_k A[m,k] * B[n,k] + bias[n]
// TM x 128 tile, BK=64 (128 B rows = 8 x 16B blocks), 256 threads (4 waves),
// 16x16x32 MFMA. LDS rows XOR-swizzled (slot = blk ^ (row&7)) -> fragment
// ds_read_b128 are conflict-free.
// Config search CLOSED (measured): QKV = TM=128/DB=0 (TM=64 R9: +5us;
// DB=1 R7: neutral). Out-proj = TM=32/DB=1 (TM=64/128 R2/R3: slower;
// DB=1 R6: helps this latency-bound small GEMM).
// XCD-locality swizzle: groups of 8 consecutive linear block IDs share the
// same col-tile. (gridDim.y must be a multiple of 8.)
// MODE 0: fp32 out [M, Ndim] row-major
// MODE 1: QKV epilogue -> bf16 Q,K head-split [B,H,T,Dh] (Q pre-scaled by
//         SCALE_Q); V written TRANSPOSED [B,H,Dh,T] with keys permuted per
//         32-key group (key h*16+g*4+r -> slot g*8+h*4+r) to match the attn
//         16x16 PV MFMA k-slot order.
// ---------------------------------------------------------------------------
template <int MODE, int TM, int DB>
__global__ __launch_bounds__(256) void gemm_bt_kernel(
    const unsigned short* __restrict__ A, const unsigned short* __restrict__ Bm,
    const float* __restrict__ bias, const int Kdim, const int Ndim,
    float* __restrict__ Cout,
    unsigned short* __restrict__ Qo, unsigned short* __restrict__ Ko,
    unsigned short* __restrict__ Vo)
{
    constexpr int IW  = TM / 32;           // acc row-frags per wave
    constexpr int NCH = (TM + 128) / 8;    // 1 KB staging chunks (8 rows each)
    constexpr int TB  = (TM + 128) * 128;  // bytes per LDS buffer
    __shared__ unsigned short Sm[(TM + 128) * 64 * (DB ? 2 : 1)];
    const int tid  = threadIdx.x;
    const int lane = tid & 63, wv = tid >> 6;
    const int l15  = lane & 15, l4 = lane >> 4;
    const int wr   = wv >> 1,  wc = wv & 1;

    // swizzle (gridDim.y must be a multiple of 8)
    const int lin = blockIdx.y * gridDim.x + blockIdx.x;
    const int gx  = (lin >> 3) % gridDim.x;
    const int gy  = (lin / (8 * gridDim.x)) * 8 + (lin & 7);
    const int row0 = gy * TM, col0 = gx * 128;

    auto stage = [&](int k0, int b) {
        #pragma unroll
        for (int ch0 = 0; ch0 < NCH; ch0 += 4) {   // NCH % 4 == 0
            const int ch = ch0 + wv;           // wave-uniform per call
            const int offb = ch * 1024;
            const int off  = offb + lane * 16;
            const int r  = off >> 7;           // row in [0, TM+128)
            const int bl = (off & 127) >> 4;   // 16B block within 128 B row
            const int gc = (bl ^ (r & 7)) << 3;    // swizzled element col
            const unsigned short* src = (r < TM)
                ? A  + (size_t)(row0 + r) * Kdim + k0 + gc
                : Bm + (size_t)(col0 + (r - TM)) * Kdim + k0 + gc;
            async_copy16(src, (char*)Sm + b * TB + offb);
        }
    };

    f32x4 acc[IW][4];
    #pragma unroll
    for (int i = 0; i < IW; ++i)
        #pragma unroll
        for (int j = 0; j < 4; ++j)
            acc[i][j] = (f32x4){0.f, 0.f, 0.f, 0.f};

    if (DB) stage(0, 0);

    for (int k0 = 0, it = 0; k0 < Kdim; k0 += 64, ++it) {
        const int cur = DB ? (it & 1) : 0;
        __syncthreads();                 // DB=0: prev ds_reads done.
                                         // DB=1: buf[cur] staged (vmcnt drain)
                                         //       + buf[cur^1] readers done.
        if (DB) {
            if (k0 + 64 < Kdim) stage(k0 + 64, cur ^ 1);
        } else {
            stage(k0, 0);
            __syncthreads();             // drains vmcnt -> tiles ready
        }
        const char* Sb_ = (const char*)Sm + cur * TB;

        #pragma unroll
        for (int c = 0; c < 2; ++c) {          // k halves of the 64-wide tile
            bf16x8 af[IW], bfr[4];
            #pragma unroll
            for (int i = 0; i < IW; ++i) {
                const int row = wr * (TM / 2) + i * 16 + l15;
                af[i] = *(const bf16x8*)(Sb_ +
                        row * 128 + (((c << 2) + l4) ^ (row & 7)) * 16);
            }
            #pragma unroll
            for (int j = 0; j < 4; ++j) {
                const int row = TM + wc * 64 + j * 16 + l15;
                bfr[j] = *(const bf16x8*)(Sb_ +
                        row * 128 + (((c << 2) + l4) ^ (row & 7)) * 16);
            }
            #pragma unroll
            for (int i = 0; i < IW; ++i)
                #pragma unroll
                for (int j = 0; j < 4; ++j)
                    acc[i][j] = __builtin_amdgcn_mfma_f32_16x16x32_bf16(af[i], bfr[j], acc[i][j], 0, 0, 0);
        }
    }

    // C/D layout: col = lane&15, row = (lane>>4)*4 + reg
    if (MODE == 0) {
        #pragma unroll
        for (int j = 0; j < 4; ++j) {
            const int n = col0 + wc * 64 + j * 16 + l15;
            const float bv_ = bias[n];
            #pragma unroll
            for (int i = 0; i < IW; ++i) {
                #pragma unroll
                for (int r = 0; r < 4; ++r) {
                    const int m = row0 + wr * (TM / 2) + i * 16 + l4 * 4 + r;
                    Cout[(size_t)m * Ndim + n] = acc[i][j][r] + bv_;
                }
            }
        }
    } else {
        #pragma unroll
        for (int j = 0; j < 4; ++j) {
            const int n = col0 + wc * 64 + j * 16 + l15;
            const int which = n / D;           // uniform per block (768 % 128 == 0)
            const int hd = n % D;
            const int h = hd >> 6, d = hd & 63;
            const float bv_ = bias[n];
            if (which == 2) {
                // V transposed [B,H,Dh,T], keys slot-permuted per 32-group:
                // t = h16*16 + g*4 + r  ->  tp = base32 | g*8 + h16*4 + r
                #pragma unroll
                for (int i = 0; i < IW; ++i) {
                    const int m0 = row0 + wr * (TM / 2) + i * 16 + l4 * 4;
                    const int b = m0 >> 11, t = m0 & (T - 1);
                    const int g = (t >> 2) & 3, h16 = (t >> 4) & 1;
                    const int tp = (t & ~31) | (g << 3) | (h16 << 2);
                    float4 v4;
                    v4.x = acc[i][j][0] + bv_; v4.y = acc[i][j][1] + bv_;
                    v4.z = acc[i][j][2] + bv_; v4.w = acc[i][j][3] + bv_;
                    *(ushort4*)&Vo[((size_t)(b * H + h) * Dh + d) * T + tp] = f2bf4(v4);
                }
            } else {
                const float scale = (which == 0) ? SCALE_Q : 1.0f;
                unsigned short* dst = (which == 0) ? Qo : Ko;
                #pragma unroll
                for (int i = 0; i < IW; ++i) {
                    #pragma unroll
                    for (int r = 0; r < 4; ++r) {
                        const int m = row0 + wr * (TM / 2) + i * 16 + l4 * 4 + r;
                        const int b = m >> 11, t = m & (T - 1);
                        dst[((size_t)(b * H + h) * T + t) * Dh + d] =
                            f2bf((acc[i][j][r] + bv_) * scale);
                    }
                }
            }
        }
    }
}

// ---------------------------------------------------------------------------
// Flash attention — q-blocked (R3 body, passed correctness) x KV-split
// (R8 partials, passed correctness). Each wave: 32 q rows x 64 keys/tile
// -> every K/V ds_read_b128 feeds TWO MFMAs (halves the measured per-CU
// LDS-read traffic, the binding resource: 6144 reads/CU ~= 31 us of the
// 48 us kernel). blockIdx.z picks half the key range (16 tiles) to restore
// the grid: (16, 24, 2) = 768 blocks = 3 blk/CU = 12 waves/CU (R3 alone
// fell to 1.5 blk/CU and lost; R8 alone kept per-wave work and was flat).
// Fixed-max softmax => disjoint-key partials SUM exactly; fp32 o-partial +
// rowsum to workspace, combine kernel normalizes (R8-proven).
// Failed directions (do not retry): wave K-split (R1, wrong results),
// K-from-global (R4/R5), 32x32 MFMA (R11, structural 4-way bank conflict),
// addr-hoist (R10, neutral).
// ---------------------------------------------------------------------------
__global__ __launch_bounds__(256) void attn_kernel(
    const unsigned short* __restrict__ Q, const unsigned short* __restrict__ Kg,
    const unsigned short* __restrict__ Vt,
    float* __restrict__ Po, float* __restrict__ PoL)
{
    __shared__ unsigned short Ks[2][64 * 64];
    __shared__ unsigned short Vs[2][64 * 64];
    const int bh = blockIdx.y;
    const int half = blockIdx.z;          // key range [half*1024, +1024)
    const int q0 = blockIdx.x * 128;
    const int tid = threadIdx.x, lane = tid & 63, wv = tid >> 6;
    const int l15 = lane & 15, l4 = lane >> 4;
    const unsigned short* Qp = Q  + (size_t)bh * T * Dh;
    const unsigned short* Kp = Kg + (size_t)bh * T * Dh;
    const unsigned short* Vp = Vt + (size_t)bh * Dh * T;

    // Q fragments: [qg][c]: rows q0 + wv*32 + qg*16 + l15, dh chunk c*32..+31
    bf16x8 qf[2][2];
    #pragma unroll
    for (int qg = 0; qg < 2; ++qg)
        #pragma unroll
        for (int c = 0; c < 2; ++c)
            qf[qg][c] = *(const bf16x8*)&Qp[(size_t)(q0 + wv * 32 + qg * 16 + l15) * Dh + c * 32 + l4 * 8];

    const short oneb = (short)0x3F80;     // bf16 1.0
    const bf16x8 onesf = {oneb, oneb, oneb, oneb, oneb, oneb, oneb, oneb};

    auto load_tiles = [&](int kt, int buf) {
        #pragma unroll
        for (int i = 0; i < 2; ++i) {
            const int offb = wv * 2048 + i * 1024;
            const int off  = offb + lane * 16;
            const int r = off >> 7;                     // 128 B per row
            const int blk = (off & 127) >> 4;
            const int gc = (blk ^ (r & 7)) << 3;        // swizzled element col
            async_copy16(Kp + (size_t)(kt + r) * Dh + gc, (char*)&Ks[buf][0] + offb);
            async_copy16(Vp + (size_t)r * T + kt + gc,    (char*)&Vs[buf][0] + offb);
        }
    };

    const int NT = T / 128;               // 16 tiles per half
    const int kt0 = half * NT;
    load_tiles(kt0 * 64, 0);
    f32x4 o[2][4], oL[2];
    #pragma unroll
    for (int qg = 0; qg < 2; ++qg) {
        #pragma unroll
        for (int nj = 0; nj < 4; ++nj) o[qg][nj] = (f32x4){0.f, 0.f, 0.f, 0.f};
        oL[qg] = (f32x4){0.f, 0.f, 0.f, 0.f};
    }

    for (int it = 0; it < NT; ++it) {
        const int kt64 = kt0 + it;
        const int cur = it & 1;
        __syncthreads();     // K/V(kt64) ready (vmcnt drain); buf cur^1 reads done
        if (it + 1 < NT) load_tiles((kt64 + 1) * 64, cur ^ 1);

        const char* Kb = (const char*)&Ks[cur][0];
        const char* Vb = (const char*)&Vs[cur][0];

        // ---- S^T for k16 tiles 0,1 (keys 0..31), both q-groups ----
        f32x4 Sa[2][2];      // [t][qg]
        #pragma unroll
        for (int t = 0; t < 2; ++t)
            #pragma unroll
            for (int qg = 0; qg < 2; ++qg)
                Sa[t][qg] = (f32x4){0.f, 0.f, 0.f, 0.f};
        #pragma unroll
        for (int c = 0; c < 2; ++c) {
            #pragma unroll
            for (int t = 0; t < 2; ++t) {
                const int row = t * 16 + l15;
                bf16x8 kb = *(const bf16x8*)(Kb + row * 128 + (((c << 2) + l4) ^ (row & 7)) * 16);
                #pragma unroll
                for (int qg = 0; qg < 2; ++qg)
                    Sa[t][qg] = __builtin_amdgcn_mfma_f32_16x16x32_bf16(kb, qf[qg][c], Sa[t][qg], 0, 0, 0);
            }
        }
        #pragma unroll
        for (int t = 0; t < 2; ++t)
            #pragma unroll
            for (int qg = 0; qg < 2; ++qg)
                #pragma unroll
                for (int r = 0; r < 4; ++r)
                    Sa[t][qg][r] = __builtin_amdgcn_exp2f(Sa[t][qg][r]);
        union { unsigned u[4]; bf16x8 v; } p0[2];
        #pragma unroll
        for (int qg = 0; qg < 2; ++qg) {
            p0[qg].u[0] = permpk(Sa[0][qg][1], Sa[0][qg][0]);
            p0[qg].u[1] = permpk(Sa[0][qg][3], Sa[0][qg][2]);
            p0[qg].u[2] = permpk(Sa[1][qg][1], Sa[1][qg][0]);
            p0[qg].u[3] = permpk(Sa[1][qg][3], Sa[1][qg][2]);
        }

        // ---- S^T for k16 tiles 2,3 (keys 32..63) ----
        f32x4 Sb[2][2];
        #pragma unroll
        for (int t = 0; t < 2; ++t)
            #pragma unroll
            for (int qg = 0; qg < 2; ++qg)
                Sb[t][qg] = (f32x4){0.f, 0.f, 0.f, 0.f};
        #pragma unroll
        for (int c = 0; c < 2; ++c) {
            #pragma unroll
            for (int t = 0; t < 2; ++t) {
                const int row = (t + 2) * 16 + l15;
                bf16x8 kb = *(const bf16x8*)(Kb + row * 128 + (((c << 2) + l4) ^ (row & 7)) * 16);
                #pragma unroll
                for (int qg = 0; qg < 2; ++qg)
                    Sb[t][qg] = __builtin_amdgcn_mfma_f32_16x16x32_bf16(kb, qf[qg][c], Sb[t][qg], 0, 0, 0);
            }
        }

        // ---- PV G0 (overlaps exp2 G1) ----
        #pragma unroll
        for (int qg = 0; qg < 2; ++qg)
            oL[qg] = __builtin_amdgcn_mfma_f32_16x16x32_bf16(p0[qg].v, onesf, oL[qg], 0, 0, 0);
        #pragma unroll
        for (int nj = 0; nj < 4; ++nj) {
            const int row = nj * 16 + l15;
            bf16x8 vb = *(const bf16x8*)(Vb + row * 128 + ((l4) ^ (row & 7)) * 16);
            #pragma unroll
            for (int qg = 0; qg < 2; ++qg)
                o[qg][nj] = __builtin_amdgcn_mfma_f32_16x16x32_bf16(p0[qg].v, vb, o[qg][nj], 0, 0, 0);
        }

        #pragma unroll
        for (int t = 0; t < 2; ++t)
            #pragma unroll
            for (int qg = 0; qg < 2; ++qg)
                #pragma unroll
                for (int r = 0; r < 4; ++r)
                    Sb[t][qg][r] = __builtin_amdgcn_exp2f(Sb[t][qg][r]);
        union { unsigned u[4]; bf16x8 v; } p1[2];
        #pragma unroll
        for (int qg = 0; qg < 2; ++qg) {
            p1[qg].u[0] = permpk(Sb[0][qg][1], Sb[0][qg][0]);
            p1[qg].u[1] = permpk(Sb[0][qg][3], Sb[0][qg][2]);
            p1[qg].u[2] = permpk(Sb[1][qg][1], Sb[1][qg][0]);
            p1[qg].u[3] = permpk(Sb[1][qg][3], Sb[1][qg][2]);
        }

        // ---- PV G1 ----
        #pragma unroll
        for (int qg = 0; qg < 2; ++qg)
            oL[qg] = __builtin_amdgcn_mfma_f32_16x16x32_bf16(p1[qg].v, onesf, oL[qg], 0, 0, 0);
        #pragma unroll
        for (int nj = 0; nj < 4; ++nj) {
            const int row = nj * 16 + l15;
            bf16x8 vb = *(const bf16x8*)(Vb + row * 128 + ((4 + l4) ^ (row & 7)) * 16);
            #pragma unroll
            for (int qg = 0; qg < 2; ++qg)
                o[qg][nj] = __builtin_amdgcn_mfma_f32_16x16x32_bf16(p1[qg].v, vb, o[qg][nj], 0, 0, 0);
        }
    }

    // write fp32 partials: Po[half][bh][t][64], PoL[half][bh][t]  (R8 pattern)
    const size_t base = (size_t)(half * NBH + bh) * T;
    #pragma unroll
    for (int qg = 0; qg < 2; ++qg) {
        #pragma unroll
        for (int r = 0; r < 4; ++r) {
            const int t = q0 + wv * 32 + qg * 16 + l4 * 4 + r;
            #pragma unroll
            for (int nj = 0; nj < 4; ++nj)
                Po[(base + t) * 64 + nj * 16 + l15] = o[qg][nj][r];
            if (l15 == 0) PoL[base + t] = oL[qg][r];   // all 16 cols identical
        }
    }
}

// ---------------------------------------------------------------------------
// Combine: Ctx[b,t,h*64+d] = (Po0+Po1)/(PoL0+PoL1), bf16.  (R8-proven)
// ---------------------------------------------------------------------------
__global__ __launch_bounds__(256) void combine_kernel(
    const float4* __restrict__ Po, const float* __restrict__ PoL,
    unsigned short* __restrict__ Ctx)
{
    const int idx = blockIdx.x * 256 + threadIdx.x;   // NBH*T*16 total
    const int d4 = idx & 15;
    const int rem = idx >> 4;            // bh*T + t
    const int t = rem & (T - 1), bh = rem >> 11;
    const float4 a = Po[(size_t)rem * 16 + d4];
    const float4 c = Po[(size_t)NBH * T * 16 + (size_t)rem * 16 + d4];
    const float inv = 1.0f / (PoL[rem] + PoL[NBH * T + rem]);
    const int b = bh / H, h = bh % H;
    float4 v;
    v.x = (a.x + c.x) * inv; v.y = (a.y + c.y) * inv;
    v.z = (a.z + c.z) * inv; v.w = (a.w + c.w) * inv;
    *(ushort4*)&Ctx[(size_t)(b * T + t) * D + h * 64 + d4 * 4] = f2bf4(v);
}

// ---------------------------------------------------------------------------
extern "C" void kernel_launch(void* const* d_in, const int* in_sizes, int n_in,
                              void* d_out, int out_size, void* d_ws, size_t ws_size,
                              hipStream_t stream) {
    const float* x  = (const float*)d_in[0];
    const float* Wq = (const float*)d_in[1];
    const float* bq = (const float*)d_in[2];
    const float* Wk = (const float*)d_in[3];
    const float* bk = (const float*)d_in[4];
    const float* Wv = (const float*)d_in[5];
    const float* bv = (const float*)d_in[6];
    const float* Wo = (const float*)d_in[7];
    const float* bo = (const float*)d_in[8];
    float* out = (float*)d_out;

    // workspace carve-up (~60 MB total)
    char* w = (char*)d_ws;
    auto alloc = [&](size_t bytes) {
        char* p = w; w += (bytes + 255) & ~(size_t)255; return p;
    };
    unsigned short* Xb    = (unsigned short*)alloc((size_t)M * D * 2);
    unsigned short* Wqkvb = (unsigned short*)alloc((size_t)NQKV * D * 2);
    unsigned short* Wob   = (unsigned short*)alloc((size_t)D * D * 2);
    float*          biasS = (float*)alloc((size_t)NQKV * 4);
    unsigned short* Qb    = (unsigned short*)alloc((size_t)M * D * 2);
    unsigned short* Kb    = (unsigned short*)alloc((size_t)M * D * 2);
    unsigned short* Vtb   = (unsigned short*)alloc((size_t)M * D * 2);
    unsigned short* Ctxb  = (unsigned short*)alloc((size_t)M * D * 2);
    float*          Po    = (float*)alloc((size_t)2 * NBH * T * 64 * 4);
    float*          PoL   = (float*)alloc((size_t)2 * NBH * T * 4);

    prep_kernel<<<2048, 256, 0, stream>>>(
        (const float4*)x, (const float4*)Wq, (const float4*)Wk, (const float4*)Wv,
        (const float4*)Wo, bq, bk, bv,
        (ushort4*)Xb, (ushort4*)Wqkvb, (ushort4*)Wob, biasS);

    // QKV GEMM: TM=128, DB=0 (best measured)
    gemm_bt_kernel<1, 128, 0><<<dim3(NQKV / 128, M / 128), 256, 0, stream>>>(
        Xb, Wqkvb, biasS, D, NQKV, nullptr, Qb, Kb, Vtb);

    // attention: q-blocked (32 q/wave) x KV-split(2) ->
    // grid (16, 24, 2) = 768 blocks, 3 blk/CU, 12 waves/CU
    attn_kernel<<<dim3(T / 128, NBH, 2), 256, 0, stream>>>(Qb, Kb, Vtb, Po, PoL);

    // combine partials -> Ctx bf16
    combine_kernel<<<NBH * T * 16 / 256, 256, 0, stream>>>(
        (const float4*)Po, PoL, Ctxb);

    // out-projection: TM=32 + DB=1 (best measured, R6)
    gemm_bt_kernel<0, 32, 1><<<dim3(D / 128, M / 32), 256, 0, stream>>>(
        Ctxb, Wob, bo, D, D, out, nullptr, nullptr, nullptr);
}

// Round 14
// 155.346 us; speedup vs baseline: 1.0360x; 1.0360x over previous
//
#include <hip/hip_runtime.h>
#include <math.h>

using f32x4   = __attribute__((ext_vector_type(4))) float;
using bf16x8  = __attribute__((ext_vector_type(8))) short;

constexpr int Bb = 2;
constexpr int T  = 2048;
constexpr int D  = 768;
constexpr int H  = 12;
constexpr int Dh = 64;
constexpr int M  = Bb * T;        // 4096
constexpr int NQKV = 3 * D;       // 2304
constexpr int NBH = Bb * H;       // 24
// fold 1/sqrt(Dh) * log2(e) into Q so attention uses exp2 directly
#define SCALE_Q 0.18033688011112042f

// ---------------------------------------------------------------------------
// helpers
// ---------------------------------------------------------------------------
__device__ __forceinline__ unsigned short f2bf(float f) {
    unsigned u = __float_as_uint(f);
    u += 0x7fffu + ((u >> 16) & 1u);      // RNE
    return (unsigned short)(u >> 16);
}

__device__ __forceinline__ ushort4 f2bf4(float4 f) {
    return make_ushort4(f2bf(f.x), f2bf(f.y), f2bf(f.z), f2bf(f.w));
}

// truncate-pack two fp32 -> packed bf16x2 in ONE v_perm_b32:
// result = { hi16(hi_f), hi16(lo_f) }
__device__ __forceinline__ unsigned permpk(float hi_f, float lo_f) {
    return __builtin_amdgcn_perm(__float_as_uint(hi_f), __float_as_uint(lo_f),
                                 0x07060302u);
}

// async global->LDS, 16B per lane; lds base must be wave-uniform (HW scatters
// lane l's data to base + l*16)
__device__ __forceinline__ void async_copy16(const void* g, void* lds_base) {
    __builtin_amdgcn_global_load_lds(
        (const __attribute__((address_space(1))) unsigned int*)g,
        (__attribute__((address_space(3))) unsigned int*)lds_base, 16, 0, 0);
}

// ---------------------------------------------------------------------------
// Prep: fp32 -> bf16 for X, stacked Wqkv, Wo; stack biases (fp32)
// ---------------------------------------------------------------------------
__global__ __launch_bounds__(256) void prep_kernel(
    const float4* __restrict__ x,
    const float4* __restrict__ Wq, const float4* __restrict__ Wk,
    const float4* __restrict__ Wv, const float4* __restrict__ Wo,
    const float* __restrict__ bq, const float* __restrict__ bk, const float* __restrict__ bv,
    ushort4* __restrict__ Xb, ushort4* __restrict__ Wqkvb, ushort4* __restrict__ Wob,
    float* __restrict__ biasS)
{
    const int stride = gridDim.x * 256;
    const int i0 = blockIdx.x * 256 + threadIdx.x;
    const int NX = M * D / 4;       // 786432
    const int NW = D * D / 4;       // 147456
    for (int i = i0; i < NX; i += stride) Xb[i] = f2bf4(x[i]);
    for (int i = i0; i < NW; i += stride) {
        Wqkvb[i]          = f2bf4(Wq[i]);
        Wqkvb[NW + i]     = f2bf4(Wk[i]);
        Wqkvb[2 * NW + i] = f2bf4(Wv[i]);
        Wob[i]            = f2bf4(Wo[i]);
    }
    for (int i = i0; i < D; i += stride) {
        biasS[i]         = bq[i];
        biasS[D + i]     = bk[i];
        biasS[2 * D + i] = bv[i];
    }
}

// ---------------------------------------------------------------------------
// bf16 GEMM (B^T layout): C[m,n] = sum_k A[m,k] * B[n,k] + bias[n]
// TM x 128 tile, BK=64, 256 threads (4 waves), 16x16x32 MFMA, XOR-swizzled
// LDS (slot = blk ^ (row&7)) -> conflict-free ds_read_b128.
// Config search CLOSED (measured): QKV = TM=128/DB=0; out-proj = TM=32/DB=1.
// MODE 0: fp32 out, A read via global_load_lds.
// MODE 1: QKV epilogue -> bf16 Q,K head-split (Q pre-scaled by SCALE_Q);
//         V TRANSPOSED [B,H,Dh,T], keys slot-permuted per 32-group
//         (t = h16*16+g*4+r -> tp = base32 | g*8+h16*4+r) for attn PV.
// MODE 3 (out-proj, fused attention-combine; requires TM=32, DB=1):
//         A[m,k] = bf16( (Pb0[m,k] + Pb1[m,k]) * inv ) staged in registers:
//         the two bf16 KV-split partial halves are loaded per-lane right
//         after the barrier (T14 issue-early), combined + normalized under
//         the MFMA phase, and ds_write'n to the next LDS buffer before the
//         next barrier. Normalization inv = 1/(L0[bh,t]+L1[bh,t]) is per
//         (t, head); k-tile width 64 == Dh so each staged chunk is a single
//         head -> one scalar per chunk. B side / compute / epilogue are the
//         proven path, byte-identical.
// ---------------------------------------------------------------------------
template <int MODE, int TM, int DB>
__global__ __launch_bounds__(256) void gemm_bt_kernel(
    const unsigned short* __restrict__ A, const unsigned short* __restrict__ Bm,
    const float* __restrict__ bias, const int Kdim, const int Ndim,
    float* __restrict__ Cout,
    unsigned short* __restrict__ Qo, unsigned short* __restrict__ Ko,
    unsigned short* __restrict__ Vo, const float* __restrict__ PoLp)
{
    constexpr int IW  = TM / 32;           // acc row-frags per wave
    constexpr int NCH = (TM + 128) / 8;    // 1 KB staging chunks (8 rows each)
    constexpr int TB  = (TM + 128) * 128;  // bytes per LDS buffer
    __shared__ unsigned short Sm[(TM + 128) * 64 * (DB ? 2 : 1)];
    const int tid  = threadIdx.x;
    const int lane = tid & 63, wv = tid >> 6;
    const int l15  = lane & 15, l4 = lane >> 4;
    const int wr   = wv >> 1,  wc = wv & 1;

    // swizzle (gridDim.y must be a multiple of 8)
    const int lin = blockIdx.y * gridDim.x + blockIdx.x;
    const int gx  = (lin >> 3) % gridDim.x;
    const int gy  = (lin / (8 * gridDim.x)) * 8 + (lin & 7);
    const int row0 = gy * TM, col0 = gx * 128;

    auto stage = [&](int k0, int b) {
        #pragma unroll
        for (int ch0 = 0; ch0 < NCH; ch0 += 4) {   // NCH % 4 == 0
            const int ch = ch0 + wv;           // wave-uniform per call
            const int offb = ch * 1024;
            const int off  = offb + lane * 16;
            const int r  = off >> 7;           // row in [0, TM+128)
            const int bl = (off & 127) >> 4;   // 16B block within 128 B row
            const int gc = (bl ^ (r & 7)) << 3;    // swizzled element col
            const unsigned short* src = (r < TM)
                ? A  + (size_t)(row0 + r) * Kdim + k0 + gc
                : Bm + (size_t)(col0 + (r - TM)) * Kdim + k0 + gc;
            async_copy16(src, (char*)Sm + b * TB + offb);
        }
    };

    // ---- MODE 3 helpers: A = combine of two bf16 partial halves ----
    // per-thread A-chunk geometry (TM=32: one 1 KB chunk per wave)
    const int a_offb = wv * 1024;
    const int a_off  = a_offb + lane * 16;
    const int a_r    = a_off >> 7;               // 0..31
    const int a_gc   = (((a_off & 127) >> 4) ^ (a_r & 7)) << 3;
    const int a_m    = row0 + a_r;
    const int a_b    = a_m >> 11, a_t = a_m & (T - 1);
    bf16x8 ar0, ar1; float al0, al1;
    auto issueA = [&](int k0) {
        const unsigned short* s0 = A + (size_t)a_m * Kdim + k0 + a_gc;
        ar0 = *(const bf16x8*)s0;
        ar1 = *(const bf16x8*)(s0 + (size_t)M * Kdim);    // half-1 buffer
        const int bhh = a_b * H + (k0 >> 6);              // head = k0/64
        al0 = PoLp[(size_t)bhh * T + a_t];
        al1 = PoLp[(size_t)(NBH + bhh) * T + a_t];
    };
    auto writeA = [&](int b) {
        const float inv = 1.0f / (al0 + al1);
        union { unsigned short us[8]; bf16x8 v; } cr;
        #pragma unroll
        for (int j = 0; j < 8; ++j) {
            const float f0 = __uint_as_float(((unsigned)(unsigned short)ar0[j]) << 16);
            const float f1 = __uint_as_float(((unsigned)(unsigned short)ar1[j]) << 16);
            cr.us[j] = f2bf((f0 + f1) * inv);
        }
        *(bf16x8*)((char*)Sm + b * TB + a_off) = cr.v;
    };
    auto stageB = [&](int k0, int b) {
        #pragma unroll
        for (int ch0 = 0; ch0 < 16; ch0 += 4) {
            const int ch = (TM / 8) + ch0 + wv;
            const int offb = ch * 1024;
            const int off  = offb + lane * 16;
            const int r  = off >> 7;
            const int gc = ((((off & 127) >> 4)) ^ (r & 7)) << 3;
            async_copy16(Bm + (size_t)(col0 + (r - TM)) * Kdim + k0 + gc,
                         (char*)Sm + b * TB + offb);
        }
    };

    f32x4 acc[IW][4];
    #pragma unroll
    for (int i = 0; i < IW; ++i)
        #pragma unroll
        for (int j = 0; j < 4; ++j)
            acc[i][j] = (f32x4){0.f, 0.f, 0.f, 0.f};

    if (DB) {
        if constexpr (MODE == 3) { issueA(0); stageB(0, 0); writeA(0); }
        else stage(0, 0);
    }

    for (int k0 = 0, it = 0; k0 < Kdim; k0 += 64, ++it) {
        const int cur = DB ? (it & 1) : 0;
        __syncthreads();                 // DB=0: prev ds_reads done.
                                         // DB=1: buf[cur] staged (vmcnt drain
                                         //       + ds_writes visible) and
                                         //       buf[cur^1] readers done.
        const bool more = (k0 + 64 < Kdim);
        if (DB) {
            if (more) {
                if constexpr (MODE == 3) { issueA(k0 + 64); stageB(k0 + 64, cur ^ 1); }
                else stage(k0 + 64, cur ^ 1);
            }
        } else {
            stage(k0, 0);
            __syncthreads();             // drains vmcnt -> tiles ready
        }
        const char* Sb_ = (const char*)Sm + cur * TB;

        #pragma unroll
        for (int c = 0; c < 2; ++c) {          // k halves of the 64-wide tile
            bf16x8 af[IW], bfr[4];
            #pragma unroll
            for (int i = 0; i < IW; ++i) {
                const int row = wr * (TM / 2) + i * 16 + l15;
                af[i] = *(const bf16x8*)(Sb_ +
                        row * 128 + (((c << 2) + l4) ^ (row & 7)) * 16);
            }
            #pragma unroll
            for (int j = 0; j < 4; ++j) {
                const int row = TM + wc * 64 + j * 16 + l15;
                bfr[j] = *(const bf16x8*)(Sb_ +
                        row * 128 + (((c << 2) + l4) ^ (row & 7)) * 16);
            }
            #pragma unroll
            for (int i = 0; i < IW; ++i)
                #pragma unroll
                for (int j = 0; j < 4; ++j)
                    acc[i][j] = __builtin_amdgcn_mfma_f32_16x16x32_bf16(af[i], bfr[j], acc[i][j], 0, 0, 0);
        }

        if constexpr (MODE == 3) { if (more) writeA(cur ^ 1); }
    }

    // C/D layout: col = lane&15, row = (lane>>4)*4 + reg
    if (MODE == 0 || MODE == 3) {
        #pragma unroll
        for (int j = 0; j < 4; ++j) {
            const int n = col0 + wc * 64 + j * 16 + l15;
            const float bv_ = bias[n];
            #pragma unroll
            for (int i = 0; i < IW; ++i) {
                #pragma unroll
                for (int r = 0; r < 4; ++r) {
                    const int m = row0 + wr * (TM / 2) + i * 16 + l4 * 4 + r;
                    Cout[(size_t)m * Ndim + n] = acc[i][j][r] + bv_;
                }
            }
        }
    } else {
        #pragma unroll
        for (int j = 0; j < 4; ++j) {
            const int n = col0 + wc * 64 + j * 16 + l15;
            const int which = n / D;           // uniform per block (768 % 128 == 0)
            const int hd = n % D;
            const int h = hd >> 6, d = hd & 63;
            const float bv_ = bias[n];
            if (which == 2) {
                // V transposed [B,H,Dh,T], keys slot-permuted per 32-group:
                // t = h16*16 + g*4 + r  ->  tp = base32 | g*8 + h16*4 + r
                #pragma unroll
                for (int i = 0; i < IW; ++i) {
                    const int m0 = row0 + wr * (TM / 2) + i * 16 + l4 * 4;
                    const int b = m0 >> 11, t = m0 & (T - 1);
                    const int g = (t >> 2) & 3, h16 = (t >> 4) & 1;
                    const int tp = (t & ~31) | (g << 3) | (h16 << 2);
                    float4 v4;
                    v4.x = acc[i][j][0] + bv_; v4.y = acc[i][j][1] + bv_;
                    v4.z = acc[i][j][2] + bv_; v4.w = acc[i][j][3] + bv_;
                    *(ushort4*)&Vo[((size_t)(b * H + h) * Dh + d) * T + tp] = f2bf4(v4);
                }
            } else {
                const float scale = (which == 0) ? SCALE_Q : 1.0f;
                unsigned short* dst = (which == 0) ? Qo : Ko;
                #pragma unroll
                for (int i = 0; i < IW; ++i) {
                    #pragma unroll
                    for (int r = 0; r < 4; ++r) {
                        const int m = row0 + wr * (TM / 2) + i * 16 + l4 * 4 + r;
                        const int b = m >> 11, t = m & (T - 1);
                        dst[((size_t)(b * H + h) * T + t) * Dh + d] =
                            f2bf((acc[i][j][r] + bv_) * scale);
                    }
                }
            }
        }
    }
}

// ---------------------------------------------------------------------------
// Flash attention — q-blocked (32 q/wave) x KV-split(2). R13 body VERBATIM
// (passed, 44.1 us, 0 conflicts): every K/V ds_read_b128 feeds TWO MFMAs
// (halves the binding per-CU LDS-read traffic); blockIdx.z picks half the
// key range so grid stays (16,24,2)=768 blocks = 3 blk/CU = 12 waves/CU.
// CHANGED vs R13 (the only edit): partials are written as BF16 in the
// out-projection's A layout (Pb[half][(b*T+t)*D + h*64+d]) + fp32 rowsums
// PoL[half][bh][t]; the separate combine kernel is GONE — the out-proj
// (MODE 3) fuses (P0+P1)*inv during its A-staging.
// Failed directions (do not retry): wave K-split (R1), K-from-global
// (R4/R5), 32x32 MFMA (R11, structural bank conflict), addr-hoist (R10).
// ---------------------------------------------------------------------------
__global__ __launch_bounds__(256) void attn_kernel(
    const unsigned short* __restrict__ Q, const unsigned short* __restrict__ Kg,
    const unsigned short* __restrict__ Vt,
    unsigned short* __restrict__ Pb, float* __restrict__ PoL)
{
    __shared__ unsigned short Ks[2][64 * 64];
    __shared__ unsigned short Vs[2][64 * 64];
    const int bh = blockIdx.y;
    const int half = blockIdx.z;          // key range [half*1024, +1024)
    const int q0 = blockIdx.x * 128;
    const int tid = threadIdx.x, lane = tid & 63, wv = tid >> 6;
    const int l15 = lane & 15, l4 = lane >> 4;
    const unsigned short* Qp = Q  + (size_t)bh * T * Dh;
    const unsigned short* Kp = Kg + (size_t)bh * T * Dh;
    const unsigned short* Vp = Vt + (size_t)bh * Dh * T;

    // Q fragments: [qg][c]: rows q0 + wv*32 + qg*16 + l15, dh chunk c*32..+31
    bf16x8 qf[2][2];
    #pragma unroll
    for (int qg = 0; qg < 2; ++qg)
        #pragma unroll
        for (int c = 0; c < 2; ++c)
            qf[qg][c] = *(const bf16x8*)&Qp[(size_t)(q0 + wv * 32 + qg * 16 + l15) * Dh + c * 32 + l4 * 8];

    const short oneb = (short)0x3F80;     // bf16 1.0
    const bf16x8 onesf = {oneb, oneb, oneb, oneb, oneb, oneb, oneb, oneb};

    auto load_tiles = [&](int kt, int buf) {
        #pragma unroll
        for (int i = 0; i < 2; ++i) {
            const int offb = wv * 2048 + i * 1024;
            const int off  = offb + lane * 16;
            const int r = off >> 7;                     // 128 B per row
            const int blk = (off & 127) >> 4;
            const int gc = (blk ^ (r & 7)) << 3;        // swizzled element col
            async_copy16(Kp + (size_t)(kt + r) * Dh + gc, (char*)&Ks[buf][0] + offb);
            async_copy16(Vp + (size_t)r * T + kt + gc,    (char*)&Vs[buf][0] + offb);
        }
    };

    const int NT = T / 128;               // 16 tiles per half
    const int kt0 = half * NT;
    load_tiles(kt0 * 64, 0);
    f32x4 o[2][4], oL[2];
    #pragma unroll
    for (int qg = 0; qg < 2; ++qg) {
        #pragma unroll
        for (int nj = 0; nj < 4; ++nj) o[qg][nj] = (f32x4){0.f, 0.f, 0.f, 0.f};
        oL[qg] = (f32x4){0.f, 0.f, 0.f, 0.f};
    }

    for (int it = 0; it < NT; ++it) {
        const int kt64 = kt0 + it;
        const int cur = it & 1;
        __syncthreads();     // K/V(kt64) ready (vmcnt drain); buf cur^1 reads done
        if (it + 1 < NT) load_tiles((kt64 + 1) * 64, cur ^ 1);

        const char* Kb = (const char*)&Ks[cur][0];
        const char* Vb = (const char*)&Vs[cur][0];

        // ---- S^T for k16 tiles 0,1 (keys 0..31), both q-groups ----
        f32x4 Sa[2][2];      // [t][qg]
        #pragma unroll
        for (int t = 0; t < 2; ++t)
            #pragma unroll
            for (int qg = 0; qg < 2; ++qg)
                Sa[t][qg] = (f32x4){0.f, 0.f, 0.f, 0.f};
        #pragma unroll
        for (int c = 0; c < 2; ++c) {
            #pragma unroll
            for (int t = 0; t < 2; ++t) {
                const int row = t * 16 + l15;
                bf16x8 kb = *(const bf16x8*)(Kb + row * 128 + (((c << 2) + l4) ^ (row & 7)) * 16);
                #pragma unroll
                for (int qg = 0; qg < 2; ++qg)
                    Sa[t][qg] = __builtin_amdgcn_mfma_f32_16x16x32_bf16(kb, qf[qg][c], Sa[t][qg], 0, 0, 0);
            }
        }
        #pragma unroll
        for (int t = 0; t < 2; ++t)
            #pragma unroll
            for (int qg = 0; qg < 2; ++qg)
                #pragma unroll
                for (int r = 0; r < 4; ++r)
                    Sa[t][qg][r] = __builtin_amdgcn_exp2f(Sa[t][qg][r]);
        union { unsigned u[4]; bf16x8 v; } p0[2];
        #pragma unroll
        for (int qg = 0; qg < 2; ++qg) {
            p0[qg].u[0] = permpk(Sa[0][qg][1], Sa[0][qg][0]);
            p0[qg].u[1] = permpk(Sa[0][qg][3], Sa[0][qg][2]);
            p0[qg].u[2] = permpk(Sa[1][qg][1], Sa[1][qg][0]);
            p0[qg].u[3] = permpk(Sa[1][qg][3], Sa[1][qg][2]);
        }

        // ---- S^T for k16 tiles 2,3 (keys 32..63) ----
        f32x4 Sb[2][2];
        #pragma unroll
        for (int t = 0; t < 2; ++t)
            #pragma unroll
            for (int qg = 0; qg < 2; ++qg)
                Sb[t][qg] = (f32x4){0.f, 0.f, 0.f, 0.f};
        #pragma unroll
        for (int c = 0; c < 2; ++c) {
            #pragma unroll
            for (int t = 0; t < 2; ++t) {
                const int row = (t + 2) * 16 + l15;
                bf16x8 kb = *(const bf16x8*)(Kb + row * 128 + (((c << 2) + l4) ^ (row & 7)) * 16);
                #pragma unroll
                for (int qg = 0; qg < 2; ++qg)
                    Sb[t][qg] = __builtin_amdgcn_mfma_f32_16x16x32_bf16(kb, qf[qg][c], Sb[t][qg], 0, 0, 0);
            }
        }

        // ---- PV G0 (overlaps exp2 G1) ----
        #pragma unroll
        for (int qg = 0; qg < 2; ++qg)
            oL[qg] = __builtin_amdgcn_mfma_f32_16x16x32_bf16(p0[qg].v, onesf, oL[qg], 0, 0, 0);
        #pragma unroll
        for (int nj = 0; nj < 4; ++nj) {
            const int row = nj * 16 + l15;
            bf16x8 vb = *(const bf16x8*)(Vb + row * 128 + ((l4) ^ (row & 7)) * 16);
            #pragma unroll
            for (int qg = 0; qg < 2; ++qg)
                o[qg][nj] = __builtin_amdgcn_mfma_f32_16x16x32_bf16(p0[qg].v, vb, o[qg][nj], 0, 0, 0);
        }

        #pragma unroll
        for (int t = 0; t < 2; ++t)
            #pragma unroll
            for (int qg = 0; qg < 2; ++qg)
                #pragma unroll
                for (int r = 0; r < 4; ++r)
                    Sb[t][qg][r] = __builtin_amdgcn_exp2f(Sb[t][qg][r]);
        union { unsigned u[4]; bf16x8 v; } p1[2];
        #pragma unroll
        for (int qg = 0; qg < 2; ++qg) {
            p1[qg].u[0] = permpk(Sb[0][qg][1], Sb[0][qg][0]);
            p1[qg].u[1] = permpk(Sb[0][qg][3], Sb[0][qg][2]);
            p1[qg].u[2] = permpk(Sb[1][qg][1], Sb[1][qg][0]);
            p1[qg].u[3] = permpk(Sb[1][qg][3], Sb[1][qg][2]);
        }

        // ---- PV G1 ----
        #pragma unroll
        for (int qg = 0; qg < 2; ++qg)
            oL[qg] = __builtin_amdgcn_mfma_f32_16x16x32_bf16(p1[qg].v, onesf, oL[qg], 0, 0, 0);
        #pragma unroll
        for (int nj = 0; nj < 4; ++nj) {
            const int row = nj * 16 + l15;
            bf16x8 vb = *(const bf16x8*)(Vb + row * 128 + ((4 + l4) ^ (row & 7)) * 16);
            #pragma unroll
            for (int qg = 0; qg < 2; ++qg)
                o[qg][nj] = __builtin_amdgcn_mfma_f32_16x16x32_bf16(p1[qg].v, vb, o[qg][nj], 0, 0, 0);
        }
    }

    // write bf16 partials in out-proj A layout: Pb[half][(b*T+t)*D + h*64+d];
    // fp32 rowsums PoL[half][bh][t] (Ctx-style coalesced stores, R13 pattern)
    const int b = bh / H, h = bh % H;
    unsigned short* Pw = Pb + (size_t)half * M * D;
    #pragma unroll
    for (int qg = 0; qg < 2; ++qg) {
        #pragma unroll
        for (int r = 0; r < 4; ++r) {
            const int t = q0 + wv * 32 + qg * 16 + l4 * 4 + r;
            #pragma unroll
            for (int nj = 0; nj < 4; ++nj)
                Pw[(size_t)(b * T + t) * D + h * 64 + nj * 16 + l15] = f2bf(o[qg][nj][r]);
            if (l15 == 0) PoL[(size_t)(half * NBH + bh) * T + t] = oL[qg][r];
        }
    }
}

// ---------------------------------------------------------------------------
extern "C" void kernel_launch(void* const* d_in, const int* in_sizes, int n_in,
                              void* d_out, int out_size, void* d_ws, size_t ws_size,
                              hipStream_t stream) {
    const float* x  = (const float*)d_in[0];
    const float* Wq = (const float*)d_in[1];
    const float* bq = (const float*)d_in[2];
    const float* Wk = (const float*)d_in[3];
    const float* bk = (const float*)d_in[4];
    const float* Wv = (const float*)d_in[5];
    const float* bv = (const float*)d_in[6];
    const float* Wo = (const float*)d_in[7];
    const float* bo = (const float*)d_in[8];
    float* out = (float*)d_out;

    // workspace carve-up (~45 MB total)
    char* w = (char*)d_ws;
    auto alloc = [&](size_t bytes) {
        char* p = w; w += (bytes + 255) & ~(size_t)255; return p;
    };
    unsigned short* Xb    = (unsigned short*)alloc((size_t)M * D * 2);
    unsigned short* Wqkvb = (unsigned short*)alloc((size_t)NQKV * D * 2);
    unsigned short* Wob   = (unsigned short*)alloc((size_t)D * D * 2);
    float*          biasS = (float*)alloc((size_t)NQKV * 4);
    unsigned short* Qb    = (unsigned short*)alloc((size_t)M * D * 2);
    unsigned short* Kb    = (unsigned short*)alloc((size_t)M * D * 2);
    unsigned short* Vtb   = (unsigned short*)alloc((size_t)M * D * 2);
    unsigned short* Pb    = (unsigned short*)alloc((size_t)2 * M * D * 2);
    float*          PoL   = (float*)alloc((size_t)2 * NBH * T * 4);

    prep_kernel<<<2048, 256, 0, stream>>>(
        (const float4*)x, (const float4*)Wq, (const float4*)Wk, (const float4*)Wv,
        (const float4*)Wo, bq, bk, bv,
        (ushort4*)Xb, (ushort4*)Wqkvb, (ushort4*)Wob, biasS);

    // QKV GEMM: TM=128, DB=0 (best measured)
    gemm_bt_kernel<1, 128, 0><<<dim3(NQKV / 128, M / 128), 256, 0, stream>>>(
        Xb, Wqkvb, biasS, D, NQKV, nullptr, Qb, Kb, Vtb, nullptr);

    // attention: q-blocked (32 q/wave) x KV-split(2) ->
    // grid (16, 24, 2) = 768 blocks, 3 blk/CU, 12 waves/CU (44.1 us, R13)
    attn_kernel<<<dim3(T / 128, NBH, 2), 256, 0, stream>>>(Qb, Kb, Vtb, Pb, PoL);

    // out-projection with FUSED combine (MODE 3): A = (Pb0+Pb1)*inv staged
    // in registers under the MFMA phase; no separate combine kernel.
    gemm_bt_kernel<3, 32, 1><<<dim3(D / 128, M / 32), 256, 0, stream>>>(
        Pb, Wob, bo, D, D, out, nullptr, nullptr, nullptr, PoL);
}